// Round 3
// baseline (103271.362 us; speedup 1.0000x reference)
//
#include <hip/hip_runtime.h>

// DeepLSTM: B=32, S=512, IN=512, H=1024, 3H=3072, L=4
// out (fp32): cur [32][512][1024] | h_finals [4][32][1024] | c_finals [4][32][1024]
// ws (~192 MiB): Xp fp32 | hbuf_hi | hbuf_lo | bar
// Precision: split-bf16 (hi+lo) 3-term MFMA everywhere (~2^-16 rel); Xp fp32;
// inter-layer y fp32 staged in d_out's cur region (same shape, overwritten by layer 3);
// h carried as exact (hi,lo) bf16 planes; c in fp32 register.

typedef unsigned short ushort_t;
typedef __attribute__((ext_vector_type(4))) float f32x4;
typedef __attribute__((ext_vector_type(8))) short s16x8;
typedef __attribute__((ext_vector_type(4))) short s16x4;

__device__ __forceinline__ unsigned short f2bf(float f) {
  union { float f; unsigned u; } v; v.f = f;
  unsigned r = (v.u + 0x7fffu + ((v.u >> 16) & 1u)) >> 16;
  return (unsigned short)r;
}
__device__ __forceinline__ float bf2f(unsigned short h) {
  union { unsigned u; float f; } v; v.u = ((unsigned)h) << 16; return v.f;
}
__device__ __forceinline__ void split2(float x, short& hi, short& lo) {
  unsigned short h = f2bf(x);
  hi = (short)h;
  lo = (short)f2bf(x - bf2f(h));
}

// ---------------- split-bf16 GEMM: C[m][n] = sum_k A[m][k]*Bw[n][k] + bias[n] ----------------
// A: fp32 [M][K]; Bw: fp32 [N][K]; C: fp32 [M][N]. BM=BN=128, BK=32.
#define BM 128
#define BN 128
#define BK 32
__global__ __launch_bounds__(256) void k_gemm_split(
    const float* __restrict__ A, const float* __restrict__ Bw,
    const float* __restrict__ bias, float* __restrict__ C,
    int M, int N, int K) {
  __shared__ short Ah[BM * BK], Al[BM * BK];
  __shared__ short Bh[BN * BK], Bl[BN * BK];
  const int tid = threadIdx.x;
  const int nbm = M / BM;
  const int bm = blockIdx.x % nbm;
  const int bn = blockIdx.x / nbm;
  const int lane = tid & 63;
  const int wave = tid >> 6;
  const int wm = (wave & 1) * 64;
  const int wn = (wave >> 1) * 64;
  const int q = lane >> 4;
  f32x4 acc[4][4] = {};
  const int nk = K / BK;
  for (int kt = 0; kt < nk; ++kt) {
    __syncthreads();
    const int kb = kt * BK;
    // stage A and B tiles: 1024 float4-groups each; convert to hi/lo bf16
#pragma unroll
    for (int i = 0; i < 4; ++i) {
      int idx = tid + i * 256;            // 0..1023
      int row = idx >> 3, c4 = (idx & 7) * 4;
      f32x4 ta = *(const f32x4*)(A + (size_t)(bm * BM + row) * K + kb + c4);
      s16x4 h4, l4;
#pragma unroll
      for (int j = 0; j < 4; ++j) { short hh, ll; split2(ta[j], hh, ll); h4[j] = hh; l4[j] = ll; }
      *(s16x4*)&Ah[row * BK + c4] = h4;
      *(s16x4*)&Al[row * BK + c4] = l4;
      f32x4 tb = *(const f32x4*)(Bw + (size_t)(bn * BN + row) * K + kb + c4);
#pragma unroll
      for (int j = 0; j < 4; ++j) { short hh, ll; split2(tb[j], hh, ll); h4[j] = hh; l4[j] = ll; }
      *(s16x4*)&Bh[row * BK + c4] = h4;
      *(s16x4*)&Bl[row * BK + c4] = l4;
    }
    __syncthreads();
    s16x8 ah[4], al[4], bh[4], bl[4];
#pragma unroll
    for (int i = 0; i < 4; ++i) {
      int r = (wm + i * 16 + (lane & 15)) * BK + q * 8;
      ah[i] = *(const s16x8*)&Ah[r];
      al[i] = *(const s16x8*)&Al[r];
      int rb = (wn + i * 16 + (lane & 15)) * BK + q * 8;
      bh[i] = *(const s16x8*)&Bh[rb];
      bl[i] = *(const s16x8*)&Bl[rb];
    }
#pragma unroll
    for (int mi = 0; mi < 4; ++mi)
#pragma unroll
      for (int ni = 0; ni < 4; ++ni) {
        acc[mi][ni] = __builtin_amdgcn_mfma_f32_16x16x32_bf16(ah[mi], bh[ni], acc[mi][ni], 0, 0, 0);
        acc[mi][ni] = __builtin_amdgcn_mfma_f32_16x16x32_bf16(al[mi], bh[ni], acc[mi][ni], 0, 0, 0);
        acc[mi][ni] = __builtin_amdgcn_mfma_f32_16x16x32_bf16(ah[mi], bl[ni], acc[mi][ni], 0, 0, 0);
      }
  }
#pragma unroll
  for (int mi = 0; mi < 4; ++mi)
#pragma unroll
    for (int ni = 0; ni < 4; ++ni) {
      int col = bn * BN + wn + ni * 16 + (lane & 15);
      float bv = bias[col];
#pragma unroll
      for (int r = 0; r < 4; ++r) {
        int row = bm * BM + wm + mi * 16 + q * 4 + r;
        C[(size_t)row * N + col] = acc[mi][ni][r] + bv;
      }
    }
}

// ---------------- persistent recurrent kernel (one layer, 512 steps) ----------------
// 512 blocks x 64 threads. block: g = bid>>8 (16 batches), s = bid&255 (4 hidden units).
// LDS: split W_hh tile, 12 rows (i0-3,g0-3,o0-3) x K=1024, hi+lo = 48KB + red 1KB.
__global__ __launch_bounds__(64) void k_recurrent(
    const float* __restrict__ Xp,     // [16384][3072] fp32: x@Wih^T + b (rows m=b*512+t)
    const float* __restrict__ Whh,    // [3072][1024] fp32 (original weights)
    ushort_t* __restrict__ hhi,       // [2][32][1024] bf16 hi plane (parity 0 pre-zeroed)
    ushort_t* __restrict__ hlo,       // [2][32][1024] bf16 lo plane
    float* __restrict__ yOut,         // [32][512][1024] fp32: layer output (cur region)
    float* __restrict__ hOut,         // [32][1024] f32
    float* __restrict__ cOut,         // [32][1024] f32
    int* __restrict__ bar)            // [512] zeroed counters
{
  __shared__ short Wh[128 * 12 * 8];  // [kq][n][8] hi, 24 KB
  __shared__ short Wl[128 * 12 * 8];  // lo, 24 KB
  __shared__ float red[16][16];       // D tile: [batch][n], n: 0-3 i, 4-7 g, 8-11 o
  const int tid = threadIdx.x;
  const int lane = tid & 63;
  const int g = blockIdx.x >> 8;
  const int s = blockIdx.x & 255;
  const int b0 = g * 16;
  const int u0 = s * 4;

  // stage + split W_hh rows for this slice (one-time)
  for (int p = tid; p < 1536; p += 64) {
    int n = p >> 7, kq = p & 127;
    int row = (n < 4) ? (u0 + n) : (n < 8) ? (1024 + u0 + (n - 4)) : (2048 + u0 + (n - 8));
    const float* src = Whh + (size_t)row * 1024 + kq * 8;
    f32x4 v0 = *(const f32x4*)src;
    f32x4 v1 = *(const f32x4*)(src + 4);
    s16x4 h4, l4;
#pragma unroll
    for (int j = 0; j < 4; ++j) { short hh, ll; split2(v0[j], hh, ll); h4[j] = hh; l4[j] = ll; }
    *(s16x4*)&Wh[(kq * 12 + n) * 8] = h4;
    *(s16x4*)&Wl[(kq * 12 + n) * 8] = l4;
#pragma unroll
    for (int j = 0; j < 4; ++j) { short hh, ll; split2(v1[j], hh, ll); h4[j] = hh; l4[j] = ll; }
    *(s16x4*)&Wh[(kq * 12 + n) * 8 + 4] = h4;
    *(s16x4*)&Wl[(kq * 12 + n) * 8 + 4] = l4;
  }

  const int m = lane & 15;            // batch-in-group (A row)
  const int q = lane >> 4;            // k quad
  const bool nvalid = m < 12;
  const int eb = tid >> 2, eu = tid & 3;  // elementwise: (batch-in-group, unit)
  float c = 0.f;                      // cell state in register across all 512 steps
  __syncthreads();

  for (int t = 0; t < 512; ++t) {
    const int par = t & 1;
    const size_t hbase = (size_t)par * 32768 + (size_t)(b0 + m) * 1024 + q * 8;
    // --- matvec: D[batch][n] = sum_k h[batch][k] * W[n][k], split-bf16 3-term ---
    f32x4 a0 = {0.f, 0.f, 0.f, 0.f}, a1 = a0, a2 = a0;
#pragma unroll 8
    for (int kc = 0; kc < 32; ++kc) {
      s16x8 ahf = *(const s16x8*)&hhi[hbase + kc * 32];
      s16x8 alf = *(const s16x8*)&hlo[hbase + kc * 32];
      s16x8 bhf = {}, blf = {};
      if (nvalid) {
        bhf = *(const s16x8*)&Wh[(((kc * 4 + q) * 12) + m) * 8];
        blf = *(const s16x8*)&Wl[(((kc * 4 + q) * 12) + m) * 8];
      }
      a0 = __builtin_amdgcn_mfma_f32_16x16x32_bf16(ahf, bhf, a0, 0, 0, 0);
      a1 = __builtin_amdgcn_mfma_f32_16x16x32_bf16(alf, bhf, a1, 0, 0, 0);
      a2 = __builtin_amdgcn_mfma_f32_16x16x32_bf16(ahf, blf, a2, 0, 0, 0);
    }
#pragma unroll
    for (int r = 0; r < 4; ++r)
      red[q * 4 + r][m] = a0[r] + a1[r] + a2[r];
    __syncthreads();
    // --- elementwise cell update: one thread per (b,u) ---
    {
      const size_t mrow = (size_t)(b0 + eb) * 512 + t;
      float xi = Xp[mrow * 3072 + (u0 + eu)];
      float xg = Xp[mrow * 3072 + 1024 + (u0 + eu)];
      float xo = Xp[mrow * 3072 + 2048 + (u0 + eu)];
      float ig = xi + red[eb][eu];
      float gg = xg + red[eb][4 + eu];
      float og = xo + red[eb][8 + eu];
      float si = 1.f / (1.f + expf(-ig));
      float tg = tanhf(gg);
      c += si * tg;
      float so = 1.f / (1.f + expf(-og));
      float h = so * tanhf(c);
      short hh, hl;
      split2(h, hh, hl);
      size_t hw = (size_t)(1 - par) * 32768 + (size_t)(b0 + eb) * 1024 + (u0 + eu);
      hhi[hw] = (ushort_t)hh;
      hlo[hw] = (ushort_t)hl;
      yOut[mrow * 1024 + (u0 + eu)] = h;
      if (t == 511) {
        hOut[(size_t)(b0 + eb) * 1024 + (u0 + eu)] = h;
        cOut[(size_t)(b0 + eb) * 1024 + (u0 + eu)] = c;
      }
    }
    // --- device-scope grid barrier ---
    __threadfence();
    __syncthreads();
    if (tid == 0) {
      __hip_atomic_fetch_add(&bar[t], 1, __ATOMIC_ACQ_REL, __HIP_MEMORY_SCOPE_AGENT);
      while (__hip_atomic_load(&bar[t], __ATOMIC_ACQUIRE, __HIP_MEMORY_SCOPE_AGENT) < 512)
        __builtin_amdgcn_s_sleep(2);
    }
    __syncthreads();
    __threadfence();
  }
}

// ---------------- host ----------------
extern "C" void kernel_launch(void* const* d_in, const int* in_sizes, int n_in,
                              void* d_out, int out_size, void* d_ws, size_t ws_size,
                              hipStream_t stream) {
  const float* x     = (const float*)d_in[0];
  const float* w_ih0 = (const float*)d_in[1];
  const float* w_hh0 = (const float*)d_in[2];
  const float* b0v   = (const float*)d_in[3];
  const float* w_ihr = (const float*)d_in[4];
  const float* w_hhr = (const float*)d_in[5];
  const float* b_r   = (const float*)d_in[6];
  float* out = (float*)d_out;

  char* ws = (char*)d_ws;
  float*    Xp  = (float*)(ws);                    // 201,326,592 B
  ushort_t* hhi = (ushort_t*)(ws + 201326592);     //     131,072 B
  ushort_t* hlo = (ushort_t*)(ws + 201457664);     //     131,072 B
  int*      bar = (int*)(ws + 201588736);          //       8,192 B (~192.3 MiB total)

  float* yBuf     = out;                 // cur region doubles as inter-layer y staging
  float* hOutBase = out + 16777216;
  float* cOutBase = out + 16777216 + 131072;

  hipMemsetAsync(bar, 0, 8192, stream);

  for (int l = 0; l < 4; ++l) {
    const float* wih  = (l == 0) ? w_ih0 : (w_ihr + (size_t)(l - 1) * 3072 * 1024);
    const float* whh  = (l == 0) ? w_hh0 : (w_hhr + (size_t)(l - 1) * 3072 * 1024);
    const float* bias = (l == 0) ? b0v : (b_r + (size_t)(l - 1) * 3072);
    const int K = (l == 0) ? 512 : 1024;
    const float* Ain = (l == 0) ? x : yBuf;
    dim3 ggrid((16384 / BM) * (3072 / BN));
    k_gemm_split<<<ggrid, 256, 0, stream>>>(Ain, wih, bias, Xp, 16384, 3072, K);
    hipMemsetAsync(hhi, 0, 131072, stream);
    hipMemsetAsync(hlo, 0, 131072, stream);
    float* hO = hOutBase + (size_t)l * 32768;
    float* cO = cOutBase + (size_t)l * 32768;
    int* barL = bar + l * 512;
    void* args[] = { (void*)&Xp, (void*)&whh, (void*)&hhi, (void*)&hlo, (void*)&yBuf,
                     (void*)&hO, (void*)&cO, (void*)&barL };
    if (hipLaunchCooperativeKernel((void*)k_recurrent, dim3(512), dim3(64),
                                   args, 0, stream) != hipSuccess) {
      // fallback: plain launch (512 blocks, 49KB LDS, 64 thr -> all co-resident)
      k_recurrent<<<dim3(512), dim3(64), 0, stream>>>(Xp, whh, hhi, hlo, yBuf,
                                                      hO, cO, barL);
    }
  }
}